// Round 4
// baseline (93.108 us; speedup 1.0000x reference)
//
#include <hip/hip_runtime.h>
#include <hip/hip_bf16.h>
#include <stdint.h>

typedef __attribute__((ext_vector_type(8))) short short8;
typedef __attribute__((ext_vector_type(16))) float f32x16;

namespace {
constexpr int NB = 4, NL = 2048, NH = 8, NE = 64, ND = 64;
constexpr int KVBLK = 32;
constexpr float KS = 0.125f * 1.44269504f;   // fold 1/sqrt(E)*log2(e) into Q: exp2-domain logits
constexpr int NCHUNK = 40;
constexpr int RECSZ = 8320;                  // O^T 64*128 + l 128
constexpr int BUFSZ = 9216;                  // kt 4096 + vt 5120 (one LDS buffer)
}

// Equal-size chunk table (g = 128-row strip group, tiles [t0,t1), REC = slot).
__device__ const unsigned char TG[NCHUNK] = {
  3,7,7,11,11,11,15,15,15,15, 10,10,14,14,14,14, 6,6,9,10, 13,13,13,13,
  9,9, 12,12,12,12, 2,5,5, 8,8,8, 4,4, 1, 0};
__device__ const unsigned char TT0[NCHUNK] = {
  0,0,16,0,16,32,0,16,32,48, 0,15,0,15,30,45, 0,14,0,30, 0,14,28,42,
  14,27, 0,13,26,39, 0,0,12, 0,12,24, 0,10, 0, 0};
__device__ const unsigned char TT1[NCHUNK] = {
  16,16,32,16,32,48,16,32,48,64, 15,30,15,30,45,60, 14,28,14,44, 14,28,42,56,
  27,40, 13,26,39,52, 12,12,24, 12,24,36, 10,20, 8, 4};
__device__ const unsigned char TREC[NCHUNK] = {
  3,10,11,21,22,23,36,37,38,39, 18,19,32,33,34,35, 8,9,15,20, 28,29,30,31,
  16,17, 24,25,26,27, 2,6,7, 12,13,14, 4,5, 1, 0};
__device__ const unsigned char CUMD[16] = {0,1,2,3,4,6,8,10,12,15,18,21,24,28,32,36};
__device__ const unsigned char NCHD[16] = {1,1,1,1,2,2,2,2,3,3,3,3,4,4,4,4};

__device__ __forceinline__ ushort bfb(float x) {
  __hip_bfloat16 b(x);
  return __builtin_bit_cast(ushort, b);
}
__device__ __forceinline__ uint32_t pkbf(float lo, float hi) {
  return (uint32_t)bfb(lo) | ((uint32_t)bfb(hi) << 16);
}

// ------------- main: per-chunk partials, fixed-max softmax, 1-barrier pipeline ----------
__global__ __launch_bounds__(256, 4)
void sattn_part(const float* __restrict__ Qg, const float* __restrict__ Kg,
                const float* __restrict__ Vg, float* __restrict__ W)
{
  const int id = blockIdx.x;
  const int bh = id & 31;          // consecutive blocks -> different XCDs; bh pinned per XCD
  const int e  = id >> 5;
  const int g  = TG[e];
  const int t0 = TT0[e], t1 = TT1[e];
  float* rec = W + (size_t)(bh * NCHUNK + TREC[e]) * RECSZ;
  const int b = bh >> 3, h = bh & 7;

  const int tid  = threadIdx.x;
  const int wave = tid >> 6;
  const int lane = tid & 63;
  const int ln31 = lane & 31;
  const int hi   = lane >> 5;

  __shared__ __align__(16) char smem[2 * BUFSZ];   // {kt[32][64]bf16 swz | vt[64][40]bf16 swz} x2
  char* B0 = smem;
  char* B1 = smem + BUFSZ;

  const int q0w = g * 128 + wave * 32;
  const int qi  = q0w + ln31;
  const int tw  = 4 * g + wave;    // wave's diagonal tile

  // Q fragments, pre-scaled by KS
  short8 qf[4];
  {
    const float* qp = Qg + (((size_t)b * NL + qi) * NH + h) * NE;
    #pragma unroll
    for (int st = 0; st < 4; ++st) {
      const float* qpe = qp + st * 16 + hi * 8;
      union { short8 v; uint32_t u[4]; } f;
      #pragma unroll
      for (int j = 0; j < 4; ++j)
        f.u[j] = pkbf(qpe[2 * j] * KS, qpe[2 * j + 1] * KS);
      qf[st] = f.v;
    }
  }

  f32x16 acc0, acc1;
  #pragma unroll
  for (int i = 0; i < 16; ++i) { acc0[i] = 0.f; acc1[i] = 0.f; }
  float ls = 0.f;

  const int krow = tid >> 3,        kcol = (tid & 7) * 8;   // K slice: 1 row x 8 e
  const int vrow = (tid >> 4) * 2,  vcol = (tid & 15) * 4;  // V slice: 2 rows x 4 d
  const float* kpp = Kg + (((size_t)b * NL + t0 * KVBLK + krow) * NH + h) * NE + kcol;
  const float* vpp = Vg + (((size_t)b * NL + t0 * KVBLK + vrow) * NH + h) * ND + vcol;
  constexpr int KSTEP = KVBLK * NH * NE;

  auto LD = [&](int tn, float4& ka, float4& kb, float4& va, float4& vb) {
    const float* kp = kpp + (size_t)(tn - t0) * KSTEP;
    const float* vp = vpp + (size_t)(tn - t0) * KSTEP;
    ka = *(const float4*)kp;  kb = *(const float4*)(kp + 4);
    va = *(const float4*)vp;  vb = *(const float4*)(vp + NH * ND);
  };
  auto STG = [&](char* buf, const float4& ka, const float4& kb,
                 const float4& va, const float4& vb) {
    uint32_t* kd = (uint32_t*)(buf + krow * 128 + ((kcol * 2) ^ ((krow & 7) << 4)));
    kd[0] = pkbf(ka.x, ka.y); kd[1] = pkbf(ka.z, ka.w);
    kd[2] = pkbf(kb.x, kb.y); kd[3] = pkbf(kb.z, kb.w);
    char* vb_ = buf + 4096;
    const int sw = vrow * 2;
    *(uint32_t*)(vb_ + (vcol+0)*80 + (sw ^ ((((vcol+0)>>3)&3)<<4))) = pkbf(va.x, vb.x);
    *(uint32_t*)(vb_ + (vcol+1)*80 + (sw ^ ((((vcol+1)>>3)&3)<<4))) = pkbf(va.y, vb.y);
    *(uint32_t*)(vb_ + (vcol+2)*80 + (sw ^ ((((vcol+2)>>3)&3)<<4))) = pkbf(va.z, vb.z);
    *(uint32_t*)(vb_ + (vcol+3)*80 + (sw ^ ((((vcol+3)>>3)&3)<<4))) = pkbf(va.w, vb.w);
  };

  auto COMPUTE = [&](int t, const char* buf) {
    const int kv0 = t * KVBLK;
    f32x16 s;
    #pragma unroll
    for (int i = 0; i < 16; ++i) s[i] = 0.f;
    const char* kb_ = buf + ln31 * 128;
    const int   ksw = (ln31 & 7) << 4;
    __builtin_amdgcn_s_setprio(1);
    #pragma unroll
    for (int st = 0; st < 4; ++st) {
      short8 kf = *(const short8*)(kb_ + ((st * 32 + hi * 16) ^ ksw));
      s = __builtin_amdgcn_mfma_f32_32x32x16_bf16(kf, qf[st], s, 0, 0, 0);
    }
    __builtin_amdgcn_s_setprio(0);

    const int delta = q0w - kv0;
    const int qrelh = (qi - kv0) - 4 * hi;
    float ps0 = 0, ps1 = 0;
    if (t == tw) {            // diagonal: causal + pow2
      #pragma unroll
      for (int r = 0; r < 16; ++r) {
        const int cr = (r & 3) + 8 * (r >> 2);
        int diff = qrelh - cr;
        float lg = s[r];
        bool p2 = (diff > 1) & ((diff & (diff - 1)) == 0);
        lg = p2 ? 0.f : lg;
        lg = (diff < 0) ? -__builtin_inff() : lg;
        float p = exp2f(lg);
        s[r] = p; (r & 1 ? ps1 : ps0) += p;
      }
    } else {
      int pmax = 1 << (31 - __clz(delta + 31));
      if (pmax >= delta - 31) {   // pow2 stride window intersects tile
        #pragma unroll
        for (int r = 0; r < 16; ++r) {
          const int cr = (r & 3) + 8 * (r >> 2);
          int diff = qrelh - cr;
          bool p2 = (diff > 1) & ((diff & (diff - 1)) == 0);
          float p = exp2f(p2 ? 0.f : s[r]);
          s[r] = p; (r & 1 ? ps1 : ps0) += p;
        }
      } else {                    // clean: bare exp2
        #pragma unroll
        for (int r = 0; r < 16; ++r) {
          float p = exp2f(s[r]);
          s[r] = p; (r & 1 ? ps1 : ps0) += p;
        }
      }
    }
    ls += ps0 + ps1;

    uint32_t w0 = pkbf(s[0],  s[1]),  w1 = pkbf(s[2],  s[3]);
    uint32_t w2 = pkbf(s[4],  s[5]),  w3 = pkbf(s[6],  s[7]);
    uint32_t w4 = pkbf(s[8],  s[9]),  w5 = pkbf(s[10], s[11]);
    uint32_t w6 = pkbf(s[12], s[13]), w7 = pkbf(s[14], s[15]);
    uint32_t y0 = __shfl_xor(hi ? w0 : w2, 32);
    uint32_t y1 = __shfl_xor(hi ? w1 : w3, 32);
    uint32_t y2 = __shfl_xor(hi ? w4 : w6, 32);
    uint32_t y3 = __shfl_xor(hi ? w5 : w7, 32);
    union { short8 v; uint32_t u[4]; } f0, f1;
    if (hi == 0) {
      f0.u[0] = w0; f0.u[1] = w1; f0.u[2] = y0; f0.u[3] = y1;
      f1.u[0] = w4; f1.u[1] = w5; f1.u[2] = y2; f1.u[3] = y3;
    } else {
      f0.u[0] = y0; f0.u[1] = y1; f0.u[2] = w2; f0.u[3] = w3;
      f1.u[0] = y2; f1.u[1] = y3; f1.u[2] = w6; f1.u[3] = w7;
    }

    const char* vb_ = buf + 4096;
    const int d0 = ln31,      sw0 = ((d0 >> 3) & 3) << 4;
    const int d1 = 32 + ln31, sw1 = ((d1 >> 3) & 3) << 4;
    short8 a00 = *(const short8*)(vb_ + d0 * 80 + ((hi * 16) ^ sw0));
    short8 a01 = *(const short8*)(vb_ + d0 * 80 + ((32 + hi * 16) ^ sw0));
    short8 a10 = *(const short8*)(vb_ + d1 * 80 + ((hi * 16) ^ sw1));
    short8 a11 = *(const short8*)(vb_ + d1 * 80 + ((32 + hi * 16) ^ sw1));
    __builtin_amdgcn_s_setprio(1);
    acc0 = __builtin_amdgcn_mfma_f32_32x32x16_bf16(a00, f0.v, acc0, 0, 0, 0);
    acc0 = __builtin_amdgcn_mfma_f32_32x32x16_bf16(a01, f1.v, acc0, 0, 0, 0);
    acc1 = __builtin_amdgcn_mfma_f32_32x32x16_bf16(a10, f0.v, acc1, 0, 0, 0);
    acc1 = __builtin_amdgcn_mfma_f32_32x32x16_bf16(a11, f1.v, acc1, 0, 0, 0);
    __builtin_amdgcn_s_setprio(0);
  };

  // ---- pipeline: 1 barrier/tile; loads issued at iter top, drained at iter-end barrier ----
  float4 ka0, kb0, va0, vb0, ka1, kb1, va1, vb1;
  LD(t0, ka0, kb0, va0, vb0);
  STG(B0, ka0, kb0, va0, vb0);        // tile t0 -> buf0 (waits its own loads)
  LD(t0 + 1, ka1, kb1, va1, vb1);     // tile t0+1 in regs
  __syncthreads();

  int t = t0;
  while (true) {
    // even phase: compute B0(t), write rs1(t+1)->B1, issue loads(t+2)->rs0
    int tn = (t + 2 < t1) ? t + 2 : t1 - 1;
    LD(tn, ka0, kb0, va0, vb0);
    STG(B1, ka1, kb1, va1, vb1);
    if (t <= tw) COMPUTE(t, B0);
    __syncthreads();
    if (++t >= t1) break;
    // odd phase
    tn = (t + 2 < t1) ? t + 2 : t1 - 1;
    LD(tn, ka1, kb1, va1, vb1);
    STG(B0, ka0, kb0, va0, vb0);
    if (t <= tw) COMPUTE(t, B1);
    __syncthreads();
    if (++t >= t1) break;
  }

  // ---- epilogue: unnormalized O^T partial + l, coalesced ----
  ls += __shfl_xor(ls, 32);
  #pragma unroll
  for (int r = 0; r < 16; ++r) {
    int d = (r & 3) + 8 * (r >> 2) + 4 * hi;
    rec[d * 128 + wave * 32 + ln31]        = acc0[r];
    rec[(32 + d) * 128 + wave * 32 + ln31] = acc1[r];
  }
  if (hi == 0) rec[8192 + wave * 32 + ln31] = ls;
}

// ---------------- combine: sum partials, normalize, transpose, store --------------
__global__ __launch_bounds__(256)
void sattn_combine(const float* __restrict__ W, float* __restrict__ Og)
{
  const int id = blockIdx.x;             // 1024 = 32bh * 16g * 2
  const int h2 = id & 1, g = (id >> 1) & 15, bh = id >> 5;
  const int b = bh >> 3, h = bh & 7;
  const int tid = threadIdx.x;

  __shared__ float sd[64][67];           // stride 67: bank = (3d+q)%32 -> 2-way (free)
  __shared__ float Lq[64];

  const float* rec0 = W + (size_t)(bh * NCHUNK + CUMD[g]) * RECSZ;
  const int nc = NCHD[g];

  #pragma unroll
  for (int rep = 0; rep < 4; ++rep) {
    int d  = rep * 16 + (tid >> 4);
    int q4 = (tid & 15) * 4;
    float4 a = {0.f, 0.f, 0.f, 0.f};
    for (int c = 0; c < nc; ++c) {
      float4 v = *(const float4*)(rec0 + (size_t)c * RECSZ + d * 128 + h2 * 64 + q4);
      a.x += v.x; a.y += v.y; a.z += v.z; a.w += v.w;
    }
    sd[d][q4 + 0] = a.x; sd[d][q4 + 1] = a.y;
    sd[d][q4 + 2] = a.z; sd[d][q4 + 3] = a.w;
  }
  if (tid < 64) {
    float a = 0.f;
    for (int c = 0; c < nc; ++c) a += rec0[(size_t)c * RECSZ + 8192 + h2 * 64 + tid];
    Lq[tid] = 1.0f / a;
  }
  __syncthreads();
  #pragma unroll
  for (int rep = 0; rep < 4; ++rep) {
    int q  = rep * 16 + (tid >> 4);
    int d4 = (tid & 15) * 4;
    float l = Lq[q];
    float4 o = { sd[d4][q] * l, sd[d4 + 1][q] * l, sd[d4 + 2][q] * l, sd[d4 + 3][q] * l };
    *(float4*)(Og + (((size_t)b * NL + g * 128 + h2 * 64 + q) * NH + h) * ND + d4) = o;
  }
}

// ---------------- fallback (monolithic) if ws too small --------------
__global__ __launch_bounds__(256)
void sattn_mono(const float* __restrict__ Qg, const float* __restrict__ Kg,
                const float* __restrict__ Vg, float* __restrict__ Og)
{
  const int bh = blockIdx.x;
  const int y  = blockIdx.y;
  const int qblk = (y < 8) ? (15 - y) : (y - 8);
  const int b = bh >> 3, h = bh & 7;
  const int tid  = threadIdx.x;
  const int wave = tid >> 6;
  const int lane = tid & 63;
  const int ln31 = lane & 31;
  const int hi   = lane >> 5;

  __shared__ __align__(16) union {
    struct { ushort kt[KVBLK * 64]; ushort vt[64 * 40]; } s;
    float ep[4 * 32 * 68];
  } lds;

  const int q0w = qblk * 128 + wave * 32;
  const int qi  = q0w + ln31;
  const int tw  = qblk * 4 + wave;
  const int NT  = qblk * 4 + 4;

  short8 qf[4];
  {
    const float* qp = Qg + (((size_t)b * NL + qi) * NH + h) * NE;
    #pragma unroll
    for (int st = 0; st < 4; ++st) {
      const float* qpe = qp + st * 16 + hi * 8;
      union { short8 v; uint32_t u[4]; } f;
      #pragma unroll
      for (int j = 0; j < 4; ++j) f.u[j] = pkbf(qpe[2 * j] * KS, qpe[2 * j + 1] * KS);
      qf[st] = f.v;
    }
  }
  f32x16 acc0, acc1;
  #pragma unroll
  for (int i = 0; i < 16; ++i) { acc0[i] = 0.f; acc1[i] = 0.f; }
  float ls = 0.f;

  const int krow = tid >> 3,        kcol = (tid & 7) * 8;
  const int vrow = (tid >> 4) * 2,  vcol = (tid & 15) * 4;
  const float* kpp = Kg + (((size_t)b * NL + krow) * NH + h) * NE + kcol;
  const float* vpp = Vg + (((size_t)b * NL + vrow) * NH + h) * ND + vcol;
  constexpr int KSTEP = KVBLK * NH * NE;

  float kx[8], vx[8];
  #pragma unroll
  for (int j = 0; j < 8; ++j) kx[j] = kpp[j];
  #pragma unroll
  for (int j = 0; j < 4; ++j) { vx[j] = vpp[j]; vx[4 + j] = vpp[j + NH * ND]; }

  for (int t = 0; t < NT; ++t) {
    const int kv0 = t * KVBLK;
    __syncthreads();
    {
      uint32_t* kd = (uint32_t*)((char*)lds.s.kt + krow * 128 +
                                 ((kcol * 2) ^ ((krow & 7) << 4)));
      kd[0] = pkbf(kx[0], kx[1]); kd[1] = pkbf(kx[2], kx[3]);
      kd[2] = pkbf(kx[4], kx[5]); kd[3] = pkbf(kx[6], kx[7]);
      #pragma unroll
      for (int j = 0; j < 4; ++j) {
        int d = vcol + j;
        *(uint32_t*)((char*)lds.s.vt + d * 80 +
                     ((vrow * 2) ^ (((d >> 3) & 3) << 4))) = pkbf(vx[j], vx[4 + j]);
      }
    }
    {
      int tn = (t + 1 < NT) ? t + 1 : t;
      const float* kp = kpp + (size_t)tn * KSTEP;
      const float* vp = vpp + (size_t)tn * KSTEP;
      #pragma unroll
      for (int j = 0; j < 8; ++j) kx[j] = kp[j];
      #pragma unroll
      for (int j = 0; j < 4; ++j) { vx[j] = vp[j]; vx[4 + j] = vp[j + NH * ND]; }
    }
    __syncthreads();
    if (t > tw) continue;

    f32x16 s;
    #pragma unroll
    for (int i = 0; i < 16; ++i) s[i] = 0.f;
    const char* kb  = (const char*)lds.s.kt + ln31 * 128;
    const int   ksw = (ln31 & 7) << 4;
    #pragma unroll
    for (int st = 0; st < 4; ++st) {
      short8 kf = *(const short8*)(kb + ((st * 32 + hi * 16) ^ ksw));
      s = __builtin_amdgcn_mfma_f32_32x32x16_bf16(kf, qf[st], s, 0, 0, 0);
    }
    const int delta = q0w - kv0;
    const int qrelh = (qi - kv0) - 4 * hi;
    float ps = 0.f;
    if (t == tw) {
      #pragma unroll
      for (int r = 0; r < 16; ++r) {
        const int cr = (r & 3) + 8 * (r >> 2);
        int diff = qrelh - cr;
        float lg = s[r];
        bool p2 = (diff > 1) & ((diff & (diff - 1)) == 0);
        lg = p2 ? 0.f : lg;
        lg = (diff < 0) ? -__builtin_inff() : lg;
        float p = exp2f(lg); s[r] = p; ps += p;
      }
    } else {
      int pmax = 1 << (31 - __clz(delta + 31));
      if (pmax >= delta - 31) {
        #pragma unroll
        for (int r = 0; r < 16; ++r) {
          const int cr = (r & 3) + 8 * (r >> 2);
          int diff = qrelh - cr;
          bool p2 = (diff > 1) & ((diff & (diff - 1)) == 0);
          float p = exp2f(p2 ? 0.f : s[r]); s[r] = p; ps += p;
        }
      } else {
        #pragma unroll
        for (int r = 0; r < 16; ++r) { float p = exp2f(s[r]); s[r] = p; ps += p; }
      }
    }
    ls += ps;

    uint32_t w0 = pkbf(s[0],  s[1]),  w1 = pkbf(s[2],  s[3]);
    uint32_t w2 = pkbf(s[4],  s[5]),  w3 = pkbf(s[6],  s[7]);
    uint32_t w4 = pkbf(s[8],  s[9]),  w5 = pkbf(s[10], s[11]);
    uint32_t w6 = pkbf(s[12], s[13]), w7 = pkbf(s[14], s[15]);
    uint32_t y0 = __shfl_xor(hi ? w0 : w2, 32);
    uint32_t y1 = __shfl_xor(hi ? w1 : w3, 32);
    uint32_t y2 = __shfl_xor(hi ? w4 : w6, 32);
    uint32_t y3 = __shfl_xor(hi ? w5 : w7, 32);
    union { short8 v; uint32_t u[4]; } f0, f1;
    if (hi == 0) {
      f0.u[0] = w0; f0.u[1] = w1; f0.u[2] = y0; f0.u[3] = y1;
      f1.u[0] = w4; f1.u[1] = w5; f1.u[2] = y2; f1.u[3] = y3;
    } else {
      f0.u[0] = y0; f0.u[1] = y1; f0.u[2] = w2; f0.u[3] = w3;
      f1.u[0] = y2; f1.u[1] = y3; f1.u[2] = w6; f1.u[3] = w7;
    }
    const char* vb = (const char*)lds.s.vt;
    const int d0 = ln31,      sw0 = ((d0 >> 3) & 3) << 4;
    const int d1 = 32 + ln31, sw1 = ((d1 >> 3) & 3) << 4;
    short8 a00 = *(const short8*)(vb + d0 * 80 + ((hi * 16) ^ sw0));
    short8 a01 = *(const short8*)(vb + d0 * 80 + ((32 + hi * 16) ^ sw0));
    short8 a10 = *(const short8*)(vb + d1 * 80 + ((hi * 16) ^ sw1));
    short8 a11 = *(const short8*)(vb + d1 * 80 + ((32 + hi * 16) ^ sw1));
    acc0 = __builtin_amdgcn_mfma_f32_32x32x16_bf16(a00, f0.v, acc0, 0, 0, 0);
    acc0 = __builtin_amdgcn_mfma_f32_32x32x16_bf16(a01, f1.v, acc0, 0, 0, 0);
    acc1 = __builtin_amdgcn_mfma_f32_32x32x16_bf16(a10, f0.v, acc1, 0, 0, 0);
    acc1 = __builtin_amdgcn_mfma_f32_32x32x16_bf16(a11, f1.v, acc1, 0, 0, 0);
  }

  __syncthreads();
  ls += __shfl_xor(ls, 32);
  const float inv = 1.0f / ls;
  float* ep = lds.ep + wave * (32 * 68);
  #pragma unroll
  for (int r = 0; r < 16; ++r) {
    int drow = (r & 3) + 8 * (r >> 2) + 4 * hi;
    ep[ln31 * 68 + drow]      = acc0[r] * inv;
    ep[ln31 * 68 + 32 + drow] = acc1[r] * inv;
  }
  __syncthreads();
  const float* epr = lds.ep + wave * (32 * 68);
  #pragma unroll
  for (int rep = 0; rep < 8; ++rep) {
    int q  = rep * 4 + (lane >> 4);
    int d4 = (lane & 15) * 4;
    float4 val = *(const float4*)(epr + q * 68 + d4);
    float* op = Og + (((size_t)b * NL + q0w + q) * NH + h) * ND + d4;
    *(float4*)op = val;
  }
}

extern "C" void kernel_launch(void* const* d_in, const int* in_sizes, int n_in,
                              void* d_out, int out_size, void* d_ws, size_t ws_size,
                              hipStream_t stream) {
  const float* Q = (const float*)d_in[0];
  const float* K = (const float*)d_in[1];
  const float* V = (const float*)d_in[2];
  float* O = (float*)d_out;
  const size_t need = (size_t)32 * NCHUNK * RECSZ * sizeof(float);   // 42.6 MB
  if (ws_size >= need) {
    sattn_part<<<dim3(32 * NCHUNK), dim3(256), 0, stream>>>(Q, K, V, (float*)d_ws);
    sattn_combine<<<dim3(1024), dim3(256), 0, stream>>>((const float*)d_ws, O);
  } else {
    sattn_mono<<<dim3(32, 16), dim3(256), 0, stream>>>(Q, K, V, O);
  }
}

// Round 5
// 88.240 us; speedup vs baseline: 1.0552x; 1.0552x over previous
//
#include <hip/hip_runtime.h>
#include <hip/hip_bf16.h>
#include <stdint.h>

typedef __attribute__((ext_vector_type(8))) short short8;
typedef __attribute__((ext_vector_type(16))) float f32x16;

namespace {
constexpr int NB = 4, NL = 2048, NH = 8, NE = 64, ND = 64;
constexpr int KVBLK = 32;
constexpr float KS = 0.125f * 1.44269504f;   // fold 1/sqrt(E)*log2(e) into Q: exp2-domain logits
constexpr int NCHUNK = 40;
constexpr int RECSZ = 8320;                  // O^T 64*128 + l 128
}

// Equal-size chunk table (g = 128-row strip group, tiles [t0,t1), REC = slot).
__device__ const unsigned char TG[NCHUNK] = {
  3,7,7,11,11,11,15,15,15,15, 10,10,14,14,14,14, 6,6,9,10, 13,13,13,13,
  9,9, 12,12,12,12, 2,5,5, 8,8,8, 4,4, 1, 0};
__device__ const unsigned char TT0[NCHUNK] = {
  0,0,16,0,16,32,0,16,32,48, 0,15,0,15,30,45, 0,14,0,30, 0,14,28,42,
  14,27, 0,13,26,39, 0,0,12, 0,12,24, 0,10, 0, 0};
__device__ const unsigned char TT1[NCHUNK] = {
  16,16,32,16,32,48,16,32,48,64, 15,30,15,30,45,60, 14,28,14,44, 14,28,42,56,
  27,40, 13,26,39,52, 12,12,24, 12,24,36, 10,20, 8, 4};
__device__ const unsigned char TREC[NCHUNK] = {
  3,10,11,21,22,23,36,37,38,39, 18,19,32,33,34,35, 8,9,15,20, 28,29,30,31,
  16,17, 24,25,26,27, 2,6,7, 12,13,14, 4,5, 1, 0};
__device__ const unsigned char CUMD[16] = {0,1,2,3,4,6,8,10,12,15,18,21,24,28,32,36};
__device__ const unsigned char NCHD[16] = {1,1,1,1,2,2,2,2,3,3,3,3,4,4,4,4};

__device__ __forceinline__ ushort bfb(float x) {
  __hip_bfloat16 b(x);
  return __builtin_bit_cast(ushort, b);
}
__device__ __forceinline__ uint32_t pkbf(float lo, float hi) {
  return (uint32_t)bfb(lo) | ((uint32_t)bfb(hi) << 16);
}

// ------------- main: per-chunk partials, fixed-max softmax, covered prefetch ----------
__global__ __launch_bounds__(256, 4)
void sattn_part(const float* __restrict__ Qg, const float* __restrict__ Kg,
                const float* __restrict__ Vg, float* __restrict__ W)
{
  const int id = blockIdx.x;
  const int bh = id & 31;          // consecutive blocks -> different XCDs; bh pinned per XCD
  const int e  = id >> 5;
  const int g  = TG[e];
  const int t0 = TT0[e], t1 = TT1[e];
  float* rec = W + (size_t)(bh * NCHUNK + TREC[e]) * RECSZ;
  const int b = bh >> 3, h = bh & 7;

  const int tid  = threadIdx.x;
  const int wave = tid >> 6;
  const int lane = tid & 63;
  const int ln31 = lane & 31;
  const int hi   = lane >> 5;

  __shared__ __align__(16) struct {
    ushort kt[KVBLK * 64];   // byte = key*128 + ((e*2) ^ ((key&7)<<4))
    ushort vt[64 * 40];      // byte = d*80  + ((k*2) ^ (((d>>3)&3)<<4))
  } lds;

  const int q0w = g * 128 + wave * 32;
  const int qi  = q0w + ln31;
  const int tw  = 4 * g + wave;    // wave's diagonal tile

  // Q fragments, pre-scaled by KS
  short8 qf[4];
  {
    const float* qp = Qg + (((size_t)b * NL + qi) * NH + h) * NE;
    #pragma unroll
    for (int st = 0; st < 4; ++st) {
      const float* qpe = qp + st * 16 + hi * 8;
      union { short8 v; uint32_t u[4]; } f;
      #pragma unroll
      for (int j = 0; j < 4; ++j)
        f.u[j] = pkbf(qpe[2 * j] * KS, qpe[2 * j + 1] * KS);
      qf[st] = f.v;
    }
  }

  // ones fragment (bf16 1.0) for the l row-sum MFMA
  short8 onesv;
  {
    union { short8 v; uint32_t u[4]; } o;
    #pragma unroll
    for (int j = 0; j < 4; ++j) o.u[j] = 0x3F803F80u;
    onesv = o.v;
  }

  f32x16 acc0, acc1, accl;
  #pragma unroll
  for (int i = 0; i < 16; ++i) { acc0[i] = 0.f; acc1[i] = 0.f; accl[i] = 0.f; }

  const int krow = tid >> 3,        kcol = (tid & 7) * 8;   // K slice: 1 row x 8 e
  const int vrow = (tid >> 4) * 2,  vcol = (tid & 15) * 4;  // V slice: 2 rows x 4 d
  const float* kpp = Kg + (((size_t)b * NL + t0 * KVBLK + krow) * NH + h) * NE + kcol;
  const float* vpp = Vg + (((size_t)b * NL + t0 * KVBLK + vrow) * NH + h) * ND + vcol;
  constexpr int KSTEP = KVBLK * NH * NE;

  float4 ka, kb, va, vb;   // the ONLY pipeline registers (16 floats, same as R3)
  auto LD = [&](int tn) {
    const float* kp = kpp + (size_t)(tn - t0) * KSTEP;
    const float* vp = vpp + (size_t)(tn - t0) * KSTEP;
    ka = *(const float4*)kp;  kb = *(const float4*)(kp + 4);
    va = *(const float4*)vp;  vb = *(const float4*)(vp + NH * ND);
  };
  auto STG = [&]() {
    uint32_t* kd = (uint32_t*)((char*)lds.kt + krow * 128 +
                               ((kcol * 2) ^ ((krow & 7) << 4)));
    uint4 kw = { pkbf(ka.x, ka.y), pkbf(ka.z, ka.w),
                 pkbf(kb.x, kb.y), pkbf(kb.z, kb.w) };
    *(uint4*)kd = kw;                                    // one ds_write_b128
    char* vb_ = (char*)lds.vt;
    const int sw = vrow * 2;
    *(uint32_t*)(vb_ + (vcol+0)*80 + (sw ^ ((((vcol+0)>>3)&3)<<4))) = pkbf(va.x, vb.x);
    *(uint32_t*)(vb_ + (vcol+1)*80 + (sw ^ ((((vcol+1)>>3)&3)<<4))) = pkbf(va.y, vb.y);
    *(uint32_t*)(vb_ + (vcol+2)*80 + (sw ^ ((((vcol+2)>>3)&3)<<4))) = pkbf(va.z, vb.z);
    *(uint32_t*)(vb_ + (vcol+3)*80 + (sw ^ ((((vcol+3)>>3)&3)<<4))) = pkbf(va.w, vb.w);
  };

  auto COMPUTE = [&](int t) {
    const int kv0 = t * KVBLK;
    f32x16 s;
    #pragma unroll
    for (int i = 0; i < 16; ++i) s[i] = 0.f;
    const char* kb_ = (const char*)lds.kt + ln31 * 128;
    const int   ksw = (ln31 & 7) << 4;
    __builtin_amdgcn_s_setprio(1);
    #pragma unroll
    for (int st = 0; st < 4; ++st) {
      short8 kf = *(const short8*)(kb_ + ((st * 32 + hi * 16) ^ ksw));
      s = __builtin_amdgcn_mfma_f32_32x32x16_bf16(kf, qf[st], s, 0, 0, 0);
    }
    __builtin_amdgcn_s_setprio(0);

    const int delta = q0w - kv0;
    const int qrelh = (qi - kv0) - 4 * hi;
    if (t == tw) {            // diagonal: causal + pow2
      #pragma unroll
      for (int r = 0; r < 16; ++r) {
        const int cr = (r & 3) + 8 * (r >> 2);
        int diff = qrelh - cr;
        float lg = s[r];
        bool p2 = (diff > 1) & ((diff & (diff - 1)) == 0);
        lg = p2 ? 0.f : lg;
        lg = (diff < 0) ? -__builtin_inff() : lg;
        s[r] = exp2f(lg);
      }
    } else {
      int pmax = 1 << (31 - __clz(delta + 31));
      if (pmax >= delta - 31) {   // pow2 stride window intersects tile
        #pragma unroll
        for (int r = 0; r < 16; ++r) {
          const int cr = (r & 3) + 8 * (r >> 2);
          int diff = qrelh - cr;
          bool p2 = (diff > 1) & ((diff & (diff - 1)) == 0);
          s[r] = exp2f(p2 ? 0.f : s[r]);
        }
      } else {                    // clean: bare exp2
        #pragma unroll
        for (int r = 0; r < 16; ++r) s[r] = exp2f(s[r]);
      }
    }

    uint32_t w0 = pkbf(s[0],  s[1]),  w1 = pkbf(s[2],  s[3]);
    uint32_t w2 = pkbf(s[4],  s[5]),  w3 = pkbf(s[6],  s[7]);
    uint32_t w4 = pkbf(s[8],  s[9]),  w5 = pkbf(s[10], s[11]);
    uint32_t w6 = pkbf(s[12], s[13]), w7 = pkbf(s[14], s[15]);
    uint32_t y0 = __shfl_xor(hi ? w0 : w2, 32);
    uint32_t y1 = __shfl_xor(hi ? w1 : w3, 32);
    uint32_t y2 = __shfl_xor(hi ? w4 : w6, 32);
    uint32_t y3 = __shfl_xor(hi ? w5 : w7, 32);
    union { short8 v; uint32_t u[4]; } f0, f1;
    if (hi == 0) {
      f0.u[0] = w0; f0.u[1] = w1; f0.u[2] = y0; f0.u[3] = y1;   // keys 0..15
      f1.u[0] = w4; f1.u[1] = w5; f1.u[2] = y2; f1.u[3] = y3;   // keys 16..31
    } else {
      f0.u[0] = y0; f0.u[1] = y1; f0.u[2] = w2; f0.u[3] = w3;
      f1.u[0] = y2; f1.u[1] = y3; f1.u[2] = w6; f1.u[3] = w7;
    }

    const char* vb_ = (const char*)lds.vt;
    const int d0 = ln31,      sw0 = ((d0 >> 3) & 3) << 4;
    const int d1 = 32 + ln31, sw1 = ((d1 >> 3) & 3) << 4;
    short8 a00 = *(const short8*)(vb_ + d0 * 80 + ((hi * 16) ^ sw0));
    short8 a01 = *(const short8*)(vb_ + d0 * 80 + ((32 + hi * 16) ^ sw0));
    short8 a10 = *(const short8*)(vb_ + d1 * 80 + ((hi * 16) ^ sw1));
    short8 a11 = *(const short8*)(vb_ + d1 * 80 + ((32 + hi * 16) ^ sw1));
    __builtin_amdgcn_s_setprio(1);
    acc0 = __builtin_amdgcn_mfma_f32_32x32x16_bf16(a00, f0.v, acc0, 0, 0, 0);
    acc0 = __builtin_amdgcn_mfma_f32_32x32x16_bf16(a01, f1.v, acc0, 0, 0, 0);
    acc1 = __builtin_amdgcn_mfma_f32_32x32x16_bf16(a10, f0.v, acc1, 0, 0, 0);
    acc1 = __builtin_amdgcn_mfma_f32_32x32x16_bf16(a11, f1.v, acc1, 0, 0, 0);
    accl = __builtin_amdgcn_mfma_f32_32x32x16_bf16(onesv, f0.v, accl, 0, 0, 0);
    accl = __builtin_amdgcn_mfma_f32_32x32x16_bf16(onesv, f1.v, accl, 0, 0, 0);
    __builtin_amdgcn_s_setprio(0);
  };

  // ---- pipeline: LD issued AFTER the ready-barrier, drained at NEXT top-barrier ----
  LD(t0);
  STG();                                    // waits its own loads
  __syncthreads();                          // tile t0 visible (no vmem outstanding)
  LD(t0 + 1 < t1 ? t0 + 1 : t1 - 1);        // covered by COMPUTE(t0)
  for (int t = t0; ; ) {
    if (t <= tw) COMPUTE(t);
    if (++t == t1) break;
    __syncthreads();   // readers of t-1 done; drains LD(t) issued last iter (covered)
    STG();
    __syncthreads();   // tile t visible (lgkm only; vmem already drained)
    LD(t + 1 < t1 ? t + 1 : t1 - 1);
  }

  // ---- epilogue: unnormalized O^T partial + l (accl: every reg = row-sum) ----
  #pragma unroll
  for (int r = 0; r < 16; ++r) {
    int d = (r & 3) + 8 * (r >> 2) + 4 * hi;
    rec[d * 128 + wave * 32 + ln31]        = acc0[r];
    rec[(32 + d) * 128 + wave * 32 + ln31] = acc1[r];
  }
  if (hi == 0) rec[8192 + wave * 32 + ln31] = accl[0];
}

// ---------------- combine: sum partials, normalize, transpose, store --------------
__global__ __launch_bounds__(256)
void sattn_combine(const float* __restrict__ W, float* __restrict__ Og)
{
  const int id = blockIdx.x;             // 1024 = 32bh * 16g * 2
  const int h2 = id & 1, g = (id >> 1) & 15, bh = id >> 5;
  const int b = bh >> 3, h = bh & 7;
  const int tid = threadIdx.x;

  __shared__ float sd[64][67];           // stride 67 -> conflict-light transpose
  __shared__ float Lq[64];

  const float* rec0 = W + (size_t)(bh * NCHUNK + CUMD[g]) * RECSZ;
  const int nc = NCHD[g];

  #pragma unroll
  for (int rep = 0; rep < 4; ++rep) {
    int d  = rep * 16 + (tid >> 4);
    int q4 = (tid & 15) * 4;
    float4 a = {0.f, 0.f, 0.f, 0.f};
    for (int c = 0; c < nc; ++c) {
      float4 v = *(const float4*)(rec0 + (size_t)c * RECSZ + d * 128 + h2 * 64 + q4);
      a.x += v.x; a.y += v.y; a.z += v.z; a.w += v.w;
    }
    sd[d][q4 + 0] = a.x; sd[d][q4 + 1] = a.y;
    sd[d][q4 + 2] = a.z; sd[d][q4 + 3] = a.w;
  }
  if (tid < 64) {
    float a = 0.f;
    for (int c = 0; c < nc; ++c) a += rec0[(size_t)c * RECSZ + 8192 + h2 * 64 + tid];
    Lq[tid] = 1.0f / a;
  }
  __syncthreads();
  #pragma unroll
  for (int rep = 0; rep < 4; ++rep) {
    int q  = rep * 16 + (tid >> 4);
    int d4 = (tid & 15) * 4;
    float l = Lq[q];
    float4 o = { sd[d4][q] * l, sd[d4 + 1][q] * l, sd[d4 + 2][q] * l, sd[d4 + 3][q] * l };
    *(float4*)(Og + (((size_t)b * NL + g * 128 + h2 * 64 + q) * NH + h) * ND + d4) = o;
  }
}

// ---------------- fallback (monolithic) if ws too small --------------
__global__ __launch_bounds__(256)
void sattn_mono(const float* __restrict__ Qg, const float* __restrict__ Kg,
                const float* __restrict__ Vg, float* __restrict__ Og)
{
  const int bh = blockIdx.x;
  const int y  = blockIdx.y;
  const int qblk = (y < 8) ? (15 - y) : (y - 8);
  const int b = bh >> 3, h = bh & 7;
  const int tid  = threadIdx.x;
  const int wave = tid >> 6;
  const int lane = tid & 63;
  const int ln31 = lane & 31;
  const int hi   = lane >> 5;

  __shared__ __align__(16) union {
    struct { ushort kt[KVBLK * 64]; ushort vt[64 * 40]; } s;
    float ep[4 * 32 * 68];
  } lds;

  const int q0w = qblk * 128 + wave * 32;
  const int qi  = q0w + ln31;
  const int tw  = qblk * 4 + wave;
  const int NT  = qblk * 4 + 4;

  short8 qf[4];
  {
    const float* qp = Qg + (((size_t)b * NL + qi) * NH + h) * NE;
    #pragma unroll
    for (int st = 0; st < 4; ++st) {
      const float* qpe = qp + st * 16 + hi * 8;
      union { short8 v; uint32_t u[4]; } f;
      #pragma unroll
      for (int j = 0; j < 4; ++j) f.u[j] = pkbf(qpe[2 * j] * KS, qpe[2 * j + 1] * KS);
      qf[st] = f.v;
    }
  }
  f32x16 acc0, acc1;
  #pragma unroll
  for (int i = 0; i < 16; ++i) { acc0[i] = 0.f; acc1[i] = 0.f; }
  float ls = 0.f;

  const int krow = tid >> 3,        kcol = (tid & 7) * 8;
  const int vrow = (tid >> 4) * 2,  vcol = (tid & 15) * 4;
  const float* kpp = Kg + (((size_t)b * NL + krow) * NH + h) * NE + kcol;
  const float* vpp = Vg + (((size_t)b * NL + vrow) * NH + h) * ND + vcol;
  constexpr int KSTEP = KVBLK * NH * NE;

  float kx[8], vx[8];
  #pragma unroll
  for (int j = 0; j < 8; ++j) kx[j] = kpp[j];
  #pragma unroll
  for (int j = 0; j < 4; ++j) { vx[j] = vpp[j]; vx[4 + j] = vpp[j + NH * ND]; }

  for (int t = 0; t < NT; ++t) {
    const int kv0 = t * KVBLK;
    __syncthreads();
    {
      uint32_t* kd = (uint32_t*)((char*)lds.s.kt + krow * 128 +
                                 ((kcol * 2) ^ ((krow & 7) << 4)));
      kd[0] = pkbf(kx[0], kx[1]); kd[1] = pkbf(kx[2], kx[3]);
      kd[2] = pkbf(kx[4], kx[5]); kd[3] = pkbf(kx[6], kx[7]);
      #pragma unroll
      for (int j = 0; j < 4; ++j) {
        int d = vcol + j;
        *(uint32_t*)((char*)lds.s.vt + d * 80 +
                     ((vrow * 2) ^ (((d >> 3) & 3) << 4))) = pkbf(vx[j], vx[4 + j]);
      }
    }
    {
      int tn = (t + 1 < NT) ? t + 1 : t;
      const float* kp = kpp + (size_t)tn * KSTEP;
      const float* vp = vpp + (size_t)tn * KSTEP;
      #pragma unroll
      for (int j = 0; j < 8; ++j) kx[j] = kp[j];
      #pragma unroll
      for (int j = 0; j < 4; ++j) { vx[j] = vp[j]; vx[4 + j] = vp[j + NH * ND]; }
    }
    __syncthreads();
    if (t > tw) continue;

    f32x16 s;
    #pragma unroll
    for (int i = 0; i < 16; ++i) s[i] = 0.f;
    const char* kb  = (const char*)lds.s.kt + ln31 * 128;
    const int   ksw = (ln31 & 7) << 4;
    #pragma unroll
    for (int st = 0; st < 4; ++st) {
      short8 kf = *(const short8*)(kb + ((st * 32 + hi * 16) ^ ksw));
      s = __builtin_amdgcn_mfma_f32_32x32x16_bf16(kf, qf[st], s, 0, 0, 0);
    }
    const int delta = q0w - kv0;
    const int qrelh = (qi - kv0) - 4 * hi;
    float ps = 0.f;
    if (t == tw) {
      #pragma unroll
      for (int r = 0; r < 16; ++r) {
        const int cr = (r & 3) + 8 * (r >> 2);
        int diff = qrelh - cr;
        float lg = s[r];
        bool p2 = (diff > 1) & ((diff & (diff - 1)) == 0);
        lg = p2 ? 0.f : lg;
        lg = (diff < 0) ? -__builtin_inff() : lg;
        float p = exp2f(lg); s[r] = p; ps += p;
      }
    } else {
      int pmax = 1 << (31 - __clz(delta + 31));
      if (pmax >= delta - 31) {
        #pragma unroll
        for (int r = 0; r < 16; ++r) {
          const int cr = (r & 3) + 8 * (r >> 2);
          int diff = qrelh - cr;
          bool p2 = (diff > 1) & ((diff & (diff - 1)) == 0);
          float p = exp2f(p2 ? 0.f : s[r]); s[r] = p; ps += p;
        }
      } else {
        #pragma unroll
        for (int r = 0; r < 16; ++r) { float p = exp2f(s[r]); s[r] = p; ps += p; }
      }
    }
    ls += ps;

    uint32_t w0 = pkbf(s[0],  s[1]),  w1 = pkbf(s[2],  s[3]);
    uint32_t w2 = pkbf(s[4],  s[5]),  w3 = pkbf(s[6],  s[7]);
    uint32_t w4 = pkbf(s[8],  s[9]),  w5 = pkbf(s[10], s[11]);
    uint32_t w6 = pkbf(s[12], s[13]), w7 = pkbf(s[14], s[15]);
    uint32_t y0 = __shfl_xor(hi ? w0 : w2, 32);
    uint32_t y1 = __shfl_xor(hi ? w1 : w3, 32);
    uint32_t y2 = __shfl_xor(hi ? w4 : w6, 32);
    uint32_t y3 = __shfl_xor(hi ? w5 : w7, 32);
    union { short8 v; uint32_t u[4]; } f0, f1;
    if (hi == 0) {
      f0.u[0] = w0; f0.u[1] = w1; f0.u[2] = y0; f0.u[3] = y1;
      f1.u[0] = w4; f1.u[1] = w5; f1.u[2] = y2; f1.u[3] = y3;
    } else {
      f0.u[0] = y0; f0.u[1] = y1; f0.u[2] = w2; f0.u[3] = w3;
      f1.u[0] = y2; f1.u[1] = y3; f1.u[2] = w6; f1.u[3] = w7;
    }
    const char* vb = (const char*)lds.s.vt;
    const int d0 = ln31,      sw0 = ((d0 >> 3) & 3) << 4;
    const int d1 = 32 + ln31, sw1 = ((d1 >> 3) & 3) << 4;
    short8 a00 = *(const short8*)(vb + d0 * 80 + ((hi * 16) ^ sw0));
    short8 a01 = *(const short8*)(vb + d0 * 80 + ((32 + hi * 16) ^ sw0));
    short8 a10 = *(const short8*)(vb + d1 * 80 + ((hi * 16) ^ sw1));
    short8 a11 = *(const short8*)(vb + d1 * 80 + ((32 + hi * 16) ^ sw1));
    acc0 = __builtin_amdgcn_mfma_f32_32x32x16_bf16(a00, f0.v, acc0, 0, 0, 0);
    acc0 = __builtin_amdgcn_mfma_f32_32x32x16_bf16(a01, f1.v, acc0, 0, 0, 0);
    acc1 = __builtin_amdgcn_mfma_f32_32x32x16_bf16(a10, f0.v, acc1, 0, 0, 0);
    acc1 = __builtin_amdgcn_mfma_f32_32x32x16_bf16(a11, f1.v, acc1, 0, 0, 0);
  }

  __syncthreads();
  ls += __shfl_xor(ls, 32);
  const float inv = 1.0f / ls;
  float* ep = lds.ep + wave * (32 * 68);
  #pragma unroll
  for (int r = 0; r < 16; ++r) {
    int drow = (r & 3) + 8 * (r >> 2) + 4 * hi;
    ep[ln31 * 68 + drow]      = acc0[r] * inv;
    ep[ln31 * 68 + 32 + drow] = acc1[r] * inv;
  }
  __syncthreads();
  const float* epr = lds.ep + wave * (32 * 68);
  #pragma unroll
  for (int rep = 0; rep < 8; ++rep) {
    int q  = rep * 4 + (lane >> 4);
    int d4 = (lane & 15) * 4;
    float4 val = *(const float4*)(epr + q * 68 + d4);
    float* op = Og + (((size_t)b * NL + q0w + q) * NH + h) * ND + d4;
    *(float4*)op = val;
  }
}

extern "C" void kernel_launch(void* const* d_in, const int* in_sizes, int n_in,
                              void* d_out, int out_size, void* d_ws, size_t ws_size,
                              hipStream_t stream) {
  const float* Q = (const float*)d_in[0];
  const float* K = (const float*)d_in[1];
  const float* V = (const float*)d_in[2];
  float* O = (float*)d_out;
  const size_t need = (size_t)32 * NCHUNK * RECSZ * sizeof(float);   // 42.6 MB
  if (ws_size >= need) {
    sattn_part<<<dim3(32 * NCHUNK), dim3(256), 0, stream>>>(Q, K, V, (float*)d_ws);
    sattn_combine<<<dim3(1024), dim3(256), 0, stream>>>((const float*)d_ws, O);
  } else {
    sattn_mono<<<dim3(32, 16), dim3(256), 0, stream>>>(Q, K, V, O);
  }
}

// Round 6
// 65.489 us; speedup vs baseline: 1.4217x; 1.3474x over previous
//
#include <hip/hip_runtime.h>
#include <hip/hip_bf16.h>
#include <stdint.h>

typedef __attribute__((ext_vector_type(8))) short short8;
typedef __attribute__((ext_vector_type(16))) float f32x16;

namespace {
constexpr int NB = 4, NL = 2048, NH = 8, NE = 64, ND = 64;
constexpr float KS = 0.125f * 1.44269504f;   // 1/sqrt(E) * log2(e): exp2-domain logits
constexpr int NCHUNK = 40;
constexpr int RECSZ  = 8320;                 // O^T 64*128 + l 128
constexpr int KSTEP  = 64 * NH * NE;         // floats per 64-key round
}

// Even-sized chunk table (g = 128-row strip group, tiles [t0,t1) of 32 keys each,
// all sizes even, sorted descending for dispatch). REC = CUMD[g]+rank(t0).
__device__ const unsigned char TG[40] = {
  3,7,7,10,11,11,11,14,14,15,15,15,15,
  6,6,9,9,10,10,12,12,13,13,13,13,14,14,
  2,5,5,8,8,8,9,12,12,
  4,4,1,0};
__device__ const unsigned char TT0[40] = {
  0,0,16,0,0,16,32,0,16,0,16,32,48,
  0,14,0,14,16,30,0,14,0,14,28,42,32,46,
  0,0,12,0,12,24,28,28,40,
  0,10,0,0};
__device__ const unsigned char TT1[40] = {
  16,16,32,16,16,32,48,16,32,16,32,48,64,
  14,28,14,28,30,44,14,28,14,28,42,56,46,60,
  12,12,24,12,24,36,40,40,52,
  10,20,8,4};
__device__ const unsigned char TREC[40] = {
  3,10,11,18,21,22,23,32,33,36,37,38,39,
  8,9,15,16,19,20,24,25,28,29,30,31,34,35,
  2,6,7,12,13,14,17,26,27,
  4,5,1,0};
__device__ const unsigned char CUMD[16] = {0,1,2,3,4,6,8,10,12,15,18,21,24,28,32,36};
__device__ const unsigned char NCHD[16] = {1,1,1,1,2,2,2,2,3,3,3,3,4,4,4,4};

__device__ __forceinline__ ushort bfb(float x) {
  __hip_bfloat16 b(x);
  return __builtin_bit_cast(ushort, b);
}
__device__ __forceinline__ uint32_t pkbf(float lo, float hi) {
  return (uint32_t)bfb(lo) | ((uint32_t)bfb(hi) << 16);
}

// ---- macros (NO lambdas: R4/R5 closure captures caused scratch spill traffic) ----
#define LD(RR) do {                                                         \
    const float* kp_ = kpp + (size_t)(RR) * KSTEP;                          \
    const float* vp_ = vpp + (size_t)(RR) * KSTEP;                          \
    kx0 = *(const float4*)(kp_);      kx1 = *(const float4*)(kp_ + 4);      \
    kx2 = *(const float4*)(kp_ + 8);  kx3 = *(const float4*)(kp_ + 12);     \
    vx0 = *(const float4*)(vp_);               vx1 = *(const float4*)(vp_ + NH*ND); \
    vx2 = *(const float4*)(vp_ + 2*NH*ND);     vx3 = *(const float4*)(vp_ + 3*NH*ND); \
  } while (0)

#define STG() do {                                                          \
    uint4 kwA = { pkbf(kx0.x,kx0.y), pkbf(kx0.z,kx0.w),                     \
                  pkbf(kx1.x,kx1.y), pkbf(kx1.z,kx1.w) };                   \
    uint4 kwB = { pkbf(kx2.x,kx2.y), pkbf(kx2.z,kx2.w),                     \
                  pkbf(kx3.x,kx3.y), pkbf(kx3.z,kx3.w) };                   \
    *(uint4*)((char*)lds.kt + krow*128 + ( kcol2        ^ kswz)) = kwA;     \
    *(uint4*)((char*)lds.kt + krow*128 + ((kcol2 + 16)  ^ kswz)) = kwB;     \
    _Pragma("unroll")                                                       \
    for (int j_ = 0; j_ < 4; ++j_) {                                        \
      int d_ = vd0 + j_;                                                    \
      char* vr_ = (char*)lds.vt + d_*128;                                   \
      int vs_ = (d_ & 7) << 4;                                              \
      *(uint32_t*)(vr_ + ((vk0*2    ) ^ vs_)) = pkbf(vx0[j_], vx1[j_]);     \
      *(uint32_t*)(vr_ + ((vk0*2 + 4) ^ vs_)) = pkbf(vx2[j_], vx3[j_]);     \
    }                                                                       \
  } while (0)

#define COMPUTE(TT, SUB) do {                                               \
    const int kv0_ = (TT) * 32;                                             \
    f32x16 s;                                                               \
    _Pragma("unroll")                                                       \
    for (int i_ = 0; i_ < 16; ++i_) s[i_] = 0.f;                            \
    { const char* kb_ = (const char*)lds.kt + ((SUB)*32 + ln31) * 128;      \
      _Pragma("unroll")                                                     \
      for (int st_ = 0; st_ < 4; ++st_) {                                   \
        short8 kf_ = *(const short8*)(kb_ + ((st_*32 + hi*16) ^ rsw));      \
        s = __builtin_amdgcn_mfma_f32_32x32x16_bf16(kf_, qf[st_], s, 0,0,0);\
      } }                                                                   \
    const int delta_ = q0w - kv0_;                                          \
    const int qrelh_ = (qi - kv0_) - 4 * hi;                                \
    if ((TT) == tw) {              /* diagonal: causal + pow2 */            \
      _Pragma("unroll")                                                     \
      for (int r_ = 0; r_ < 16; ++r_) {                                     \
        const int cr_ = (r_ & 3) + 8 * (r_ >> 2);                           \
        int diff_ = qrelh_ - cr_;                                           \
        float lg_ = s[r_];                                                  \
        bool p2_ = (diff_ > 1) & ((diff_ & (diff_ - 1)) == 0);              \
        lg_ = p2_ ? 0.f : lg_;                                              \
        lg_ = (diff_ < 0) ? -__builtin_inff() : lg_;                        \
        s[r_] = exp2f(lg_);                                                 \
      }                                                                     \
    } else {                                                                \
      int pmax_ = 1 << (31 - __clz(delta_ + 31));                           \
      if (pmax_ >= delta_ - 31) {  /* pow2 stride window intersects */      \
        _Pragma("unroll")                                                   \
        for (int r_ = 0; r_ < 16; ++r_) {                                   \
          const int cr_ = (r_ & 3) + 8 * (r_ >> 2);                         \
          int diff_ = qrelh_ - cr_;                                         \
          bool p2_ = (diff_ > 1) & ((diff_ & (diff_ - 1)) == 0);            \
          s[r_] = exp2f(p2_ ? 0.f : s[r_]);                                 \
        }                                                                   \
      } else {                     /* clean: bare exp2 */                   \
        _Pragma("unroll")                                                   \
        for (int r_ = 0; r_ < 16; ++r_) s[r_] = exp2f(s[r_]);               \
      }                                                                     \
    }                                                                       \
    uint32_t w0_ = pkbf(s[0],  s[1]),  w1_ = pkbf(s[2],  s[3]);             \
    uint32_t w2_ = pkbf(s[4],  s[5]),  w3_ = pkbf(s[6],  s[7]);             \
    uint32_t w4_ = pkbf(s[8],  s[9]),  w5_ = pkbf(s[10], s[11]);            \
    uint32_t w6_ = pkbf(s[12], s[13]), w7_ = pkbf(s[14], s[15]);            \
    uint32_t y0_ = __shfl_xor(hi ? w0_ : w2_, 32);                          \
    uint32_t y1_ = __shfl_xor(hi ? w1_ : w3_, 32);                          \
    uint32_t y2_ = __shfl_xor(hi ? w4_ : w6_, 32);                          \
    uint32_t y3_ = __shfl_xor(hi ? w5_ : w7_, 32);                          \
    union { short8 v; uint32_t u[4]; } f0_, f1_;                            \
    if (hi == 0) {                                                          \
      f0_.u[0] = w0_; f0_.u[1] = w1_; f0_.u[2] = y0_; f0_.u[3] = y1_;       \
      f1_.u[0] = w4_; f1_.u[1] = w5_; f1_.u[2] = y2_; f1_.u[3] = y3_;       \
    } else {                                                                \
      f0_.u[0] = y0_; f0_.u[1] = y1_; f0_.u[2] = w2_; f0_.u[3] = w3_;       \
      f1_.u[0] = y2_; f1_.u[1] = y3_; f1_.u[2] = w6_; f1_.u[3] = w7_;       \
    }                                                                       \
    { const char* vb_ = (const char*)lds.vt;                                \
      const char* vr0_ = vb_ + ln31 * 128;                                  \
      const char* vr1_ = vb_ + (32 + ln31) * 128;                           \
      short8 a00_ = *(const short8*)(vr0_ + (((SUB)*64      + hi*16) ^ rsw));\
      short8 a01_ = *(const short8*)(vr0_ + (((SUB)*64 + 32 + hi*16) ^ rsw));\
      short8 a10_ = *(const short8*)(vr1_ + (((SUB)*64      + hi*16) ^ rsw));\
      short8 a11_ = *(const short8*)(vr1_ + (((SUB)*64 + 32 + hi*16) ^ rsw));\
      acc0 = __builtin_amdgcn_mfma_f32_32x32x16_bf16(a00_, f0_.v, acc0, 0,0,0); \
      acc0 = __builtin_amdgcn_mfma_f32_32x32x16_bf16(a01_, f1_.v, acc0, 0,0,0); \
      acc1 = __builtin_amdgcn_mfma_f32_32x32x16_bf16(a10_, f0_.v, acc1, 0,0,0); \
      acc1 = __builtin_amdgcn_mfma_f32_32x32x16_bf16(a11_, f1_.v, acc1, 0,0,0); \
      accl = __builtin_amdgcn_mfma_f32_32x32x16_bf16(onesv, f0_.v, accl, 0,0,0);\
      accl = __builtin_amdgcn_mfma_f32_32x32x16_bf16(onesv, f1_.v, accl, 0,0,0);\
    }                                                                       \
  } while (0)

// ------------- main: per-chunk partials, fixed-max softmax, 64-key rounds ----------
__global__ __launch_bounds__(256, 3)
void sattn_part(const float* __restrict__ Qg, const float* __restrict__ Kg,
                const float* __restrict__ Vg, float* __restrict__ W)
{
  const int id = blockIdx.x;
  const int bh = id & 31;          // consecutive blocks -> different XCDs; bh pinned per XCD
  const int e  = id >> 5;
  const int g  = TG[e];
  const int t0 = TT0[e], t1 = TT1[e];
  float* rec = W + (size_t)(bh * NCHUNK + TREC[e]) * RECSZ;
  const int b = bh >> 3, h = bh & 7;

  const int tid  = threadIdx.x;
  const int wave = tid >> 6;
  const int lane = tid & 63;
  const int ln31 = lane & 31;
  const int hi   = lane >> 5;

  // kt: byte = key*128 + ((e*2) ^ ((key&7)<<4));  vt: byte = d*128 + ((k*2) ^ ((d&7)<<4))
  __shared__ __align__(16) struct { ushort kt[64 * 64]; ushort vt[64 * 64]; } lds;

  const int q0w = g * 128 + wave * 32;
  const int qi  = q0w + ln31;
  const int tw  = 4 * g + wave;    // wave's diagonal 32-key tile index

  // Q fragments, pre-scaled by KS
  short8 qf[4];
  {
    const float* qp = Qg + (((size_t)b * NL + qi) * NH + h) * NE;
    #pragma unroll
    for (int st = 0; st < 4; ++st) {
      const float* qpe = qp + st * 16 + hi * 8;
      union { short8 v; uint32_t u[4]; } f;
      #pragma unroll
      for (int j = 0; j < 4; ++j)
        f.u[j] = pkbf(qpe[2 * j] * KS, qpe[2 * j + 1] * KS);
      qf[st] = f.v;
    }
  }
  short8 onesv;
  {
    union { short8 v; uint32_t u[4]; } o;
    #pragma unroll
    for (int j = 0; j < 4; ++j) o.u[j] = 0x3F803F80u;
    onesv = o.v;
  }

  f32x16 acc0, acc1, accl;
  #pragma unroll
  for (int i = 0; i < 16; ++i) { acc0[i] = 0.f; acc1[i] = 0.f; accl[i] = 0.f; }

  // staging maps for a 64-key round
  const int krow = tid >> 2,        kcol = (tid & 3) * 16;  // K: 1 row x 16 e
  const int vk0  = (tid & 15) * 4,  vd0  = (tid >> 4) * 4;  // V: 4 keys x 4 d
  const int kbase = t0 * 32;
  const float* kpp = Kg + (((size_t)b * NL + kbase + krow) * NH + h) * NE + kcol;
  const float* vpp = Vg + (((size_t)b * NL + kbase + vk0 ) * NH + h) * ND + vd0;

  const int kswz  = (krow & 7) << 4;
  const int kcol2 = kcol * 2;
  const int rsw   = (ln31 & 7) << 4;   // read swizzle (K rows and both V row-halves)

  float4 kx0, kx1, kx2, kx3, vx0, vx1, vx2, vx3;

  const int nr = (t1 - t0) >> 1;       // all chunks have even tile counts
  LD(0);
  STG();
  __syncthreads();                     // round 0 visible
  if (nr > 1) LD(1);                   // covered by round-0 compute
  for (int r = 0;;) {
    const int tt = t0 + 2 * r;
    if (tt     <= tw) COMPUTE(tt,     0);
    if (tt + 1 <= tw) COMPUTE(tt + 1, 1);
    if (++r == nr) break;
    __syncthreads();                   // readers of round r-1 done; drains LD(r) (covered)
    STG();                             // regs (round r) -> LDS
    __syncthreads();                   // round r visible
    if (r + 1 < nr) LD(r + 1);         // covered by round-r compute
  }

  // ---- epilogue: unnormalized O^T partial + l (accl[0] = full row-sum) ----
  #pragma unroll
  for (int r = 0; r < 16; ++r) {
    int d = (r & 3) + 8 * (r >> 2) + 4 * hi;
    rec[d * 128 + wave * 32 + ln31]        = acc0[r];
    rec[(32 + d) * 128 + wave * 32 + ln31] = acc1[r];
  }
  if (hi == 0) rec[8192 + wave * 32 + ln31] = accl[0];
}

// ---------------- combine: sum partials, normalize, transpose, store --------------
__global__ __launch_bounds__(256)
void sattn_combine(const float* __restrict__ W, float* __restrict__ Og)
{
  const int id = blockIdx.x;             // 1024 = 32bh * 16g * 2
  const int h2 = id & 1, g = (id >> 1) & 15, bh = id >> 5;
  const int b = bh >> 3, h = bh & 7;
  const int tid = threadIdx.x;

  __shared__ float sd[64][67];
  __shared__ float Lq[64];

  const float* rec0 = W + (size_t)(bh * NCHUNK + CUMD[g]) * RECSZ;
  const int nc = NCHD[g];

  #pragma unroll
  for (int rep = 0; rep < 4; ++rep) {
    int d  = rep * 16 + (tid >> 4);
    int q4 = (tid & 15) * 4;
    float4 a = {0.f, 0.f, 0.f, 0.f};
    for (int c = 0; c < nc; ++c) {
      float4 v = *(const float4*)(rec0 + (size_t)c * RECSZ + d * 128 + h2 * 64 + q4);
      a.x += v.x; a.y += v.y; a.z += v.z; a.w += v.w;
    }
    sd[d][q4 + 0] = a.x; sd[d][q4 + 1] = a.y;
    sd[d][q4 + 2] = a.z; sd[d][q4 + 3] = a.w;
  }
  if (tid < 64) {
    float a = 0.f;
    for (int c = 0; c < nc; ++c) a += rec0[(size_t)c * RECSZ + 8192 + h2 * 64 + tid];
    Lq[tid] = 1.0f / a;
  }
  __syncthreads();
  #pragma unroll
  for (int rep = 0; rep < 4; ++rep) {
    int q  = rep * 16 + (tid >> 4);
    int d4 = (tid & 15) * 4;
    float l = Lq[q];
    float4 o = { sd[d4][q] * l, sd[d4 + 1][q] * l, sd[d4 + 2][q] * l, sd[d4 + 3][q] * l };
    *(float4*)(Og + (((size_t)b * NL + g * 128 + h2 * 64 + q) * NH + h) * ND + d4) = o;
  }
}

// ---------------- fallback (monolithic) if ws too small --------------
__global__ __launch_bounds__(256)
void sattn_mono(const float* __restrict__ Qg, const float* __restrict__ Kg,
                const float* __restrict__ Vg, float* __restrict__ Og)
{
  const int bh = blockIdx.x;
  const int y  = blockIdx.y;
  const int qblk = (y < 8) ? (15 - y) : (y - 8);
  const int b = bh >> 3, h = bh & 7;
  const int tid  = threadIdx.x;
  const int wave = tid >> 6;
  const int lane = tid & 63;
  const int ln31 = lane & 31;
  const int hi   = lane >> 5;

  __shared__ __align__(16) union {
    struct { ushort kt[32 * 64]; ushort vt[64 * 40]; } s;
    float ep[4 * 32 * 68];
  } lds;

  const int q0w = qblk * 128 + wave * 32;
  const int qi  = q0w + ln31;
  const int tw  = qblk * 4 + wave;
  const int NT  = qblk * 4 + 4;

  short8 qf[4];
  {
    const float* qp = Qg + (((size_t)b * NL + qi) * NH + h) * NE;
    #pragma unroll
    for (int st = 0; st < 4; ++st) {
      const float* qpe = qp + st * 16 + hi * 8;
      union { short8 v; uint32_t u[4]; } f;
      #pragma unroll
      for (int j = 0; j < 4; ++j) f.u[j] = pkbf(qpe[2 * j] * KS, qpe[2 * j + 1] * KS);
      qf[st] = f.v;
    }
  }
  f32x16 acc0, acc1;
  #pragma unroll
  for (int i = 0; i < 16; ++i) { acc0[i] = 0.f; acc1[i] = 0.f; }
  float ls = 0.f;

  const int krow = tid >> 3,        kcol = (tid & 7) * 8;
  const int vrow = (tid >> 4) * 2,  vcol = (tid & 15) * 4;
  const float* kpp = Kg + (((size_t)b * NL + krow) * NH + h) * NE + kcol;
  const float* vpp = Vg + (((size_t)b * NL + vrow) * NH + h) * ND + vcol;
  constexpr int KS32 = 32 * NH * NE;

  float kx[8], vx[8];
  #pragma unroll
  for (int j = 0; j < 8; ++j) kx[j] = kpp[j];
  #pragma unroll
  for (int j = 0; j < 4; ++j) { vx[j] = vpp[j]; vx[4 + j] = vpp[j + NH * ND]; }

  for (int t = 0; t < NT; ++t) {
    const int kv0 = t * 32;
    __syncthreads();
    {
      uint32_t* kd = (uint32_t*)((char*)lds.s.kt + krow * 128 +
                                 ((kcol * 2) ^ ((krow & 7) << 4)));
      kd[0] = pkbf(kx[0], kx[1]); kd[1] = pkbf(kx[2], kx[3]);
      kd[2] = pkbf(kx[4], kx[5]); kd[3] = pkbf(kx[6], kx[7]);
      #pragma unroll
      for (int j = 0; j < 4; ++j) {
        int d = vcol + j;
        *(uint32_t*)((char*)lds.s.vt + d * 80 +
                     ((vrow * 2) ^ (((d >> 3) & 3) << 4))) = pkbf(vx[j], vx[4 + j]);
      }
    }
    {
      int tn = (t + 1 < NT) ? t + 1 : t;
      const float* kp = kpp + (size_t)tn * KS32;
      const float* vp = vpp + (size_t)tn * KS32;
      #pragma unroll
      for (int j = 0; j < 8; ++j) kx[j] = kp[j];
      #pragma unroll
      for (int j = 0; j < 4; ++j) { vx[j] = vp[j]; vx[4 + j] = vp[j + NH * ND]; }
    }
    __syncthreads();
    if (t > tw) continue;

    f32x16 s;
    #pragma unroll
    for (int i = 0; i < 16; ++i) s[i] = 0.f;
    const char* kb  = (const char*)lds.s.kt + ln31 * 128;
    const int   ksw = (ln31 & 7) << 4;
    #pragma unroll
    for (int st = 0; st < 4; ++st) {
      short8 kf = *(const short8*)(kb + ((st * 32 + hi * 16) ^ ksw));
      s = __builtin_amdgcn_mfma_f32_32x32x16_bf16(kf, qf[st], s, 0, 0, 0);
    }
    const int delta = q0w - kv0;
    const int qrelh = (qi - kv0) - 4 * hi;
    float ps = 0.f;
    if (t == tw) {
      #pragma unroll
      for (int r = 0; r < 16; ++r) {
        const int cr = (r & 3) + 8 * (r >> 2);
        int diff = qrelh - cr;
        float lg = s[r];
        bool p2 = (diff > 1) & ((diff & (diff - 1)) == 0);
        lg = p2 ? 0.f : lg;
        lg = (diff < 0) ? -__builtin_inff() : lg;
        float p = exp2f(lg); s[r] = p; ps += p;
      }
    } else {
      int pmax = 1 << (31 - __clz(delta + 31));
      if (pmax >= delta - 31) {
        #pragma unroll
        for (int r = 0; r < 16; ++r) {
          const int cr = (r & 3) + 8 * (r >> 2);
          int diff = qrelh - cr;
          bool p2 = (diff > 1) & ((diff & (diff - 1)) == 0);
          float p = exp2f(p2 ? 0.f : s[r]); s[r] = p; ps += p;
        }
      } else {
        #pragma unroll
        for (int r = 0; r < 16; ++r) { float p = exp2f(s[r]); s[r] = p; ps += p; }
      }
    }
    ls += ps;

    uint32_t w0 = pkbf(s[0],  s[1]),  w1 = pkbf(s[2],  s[3]);
    uint32_t w2 = pkbf(s[4],  s[5]),  w3 = pkbf(s[6],  s[7]);
    uint32_t w4 = pkbf(s[8],  s[9]),  w5 = pkbf(s[10], s[11]);
    uint32_t w6 = pkbf(s[12], s[13]), w7 = pkbf(s[14], s[15]);
    uint32_t y0 = __shfl_xor(hi ? w0 : w2, 32);
    uint32_t y1 = __shfl_xor(hi ? w1 : w3, 32);
    uint32_t y2 = __shfl_xor(hi ? w4 : w6, 32);
    uint32_t y3 = __shfl_xor(hi ? w5 : w7, 32);
    union { short8 v; uint32_t u[4]; } f0, f1;
    if (hi == 0) {
      f0.u[0] = w0; f0.u[1] = w1; f0.u[2] = y0; f0.u[3] = y1;
      f1.u[0] = w4; f1.u[1] = w5; f1.u[2] = y2; f1.u[3] = y3;
    } else {
      f0.u[0] = y0; f0.u[1] = y1; f0.u[2] = w2; f0.u[3] = w3;
      f1.u[0] = y2; f1.u[1] = y3; f1.u[2] = w6; f1.u[3] = w7;
    }
    const char* vb = (const char*)lds.s.vt;
    const int d0 = ln31,      sw0 = ((d0 >> 3) & 3) << 4;
    const int d1 = 32 + ln31, sw1 = ((d1 >> 3) & 3) << 4;
    short8 a00 = *(const short8*)(vb + d0 * 80 + ((hi * 16) ^ sw0));
    short8 a01 = *(const short8*)(vb + d0 * 80 + ((32 + hi * 16) ^ sw0));
    short8 a10 = *(const short8*)(vb + d1 * 80 + ((hi * 16) ^ sw1));
    short8 a11 = *(const short8*)(vb + d1 * 80 + ((32 + hi * 16) ^ sw1));
    acc0 = __builtin_amdgcn_mfma_f32_32x32x16_bf16(a00, f0.v, acc0, 0, 0, 0);
    acc0 = __builtin_amdgcn_mfma_f32_32x32x16_bf16(a01, f1.v, acc0, 0, 0, 0);
    acc1 = __builtin_amdgcn_mfma_f32_32x32x16_bf16(a10, f0.v, acc1, 0, 0, 0);
    acc1 = __builtin_amdgcn_mfma_f32_32x32x16_bf16(a11, f1.v, acc1, 0, 0, 0);
  }

  __syncthreads();
  ls += __shfl_xor(ls, 32);
  const float inv = 1.0f / ls;
  float* ep = lds.ep + wave * (32 * 68);
  #pragma unroll
  for (int r = 0; r < 16; ++r) {
    int drow = (r & 3) + 8 * (r >> 2) + 4 * hi;
    ep[ln31 * 68 + drow]      = acc0[r] * inv;
    ep[ln31 * 68 + 32 + drow] = acc1[r] * inv;
  }
  __syncthreads();
  const float* epr = lds.ep + wave * (32 * 68);
  #pragma unroll
  for (int rep = 0; rep < 8; ++rep) {
    int q  = rep * 4 + (lane >> 4);
    int d4 = (lane & 15) * 4;
    float4 val = *(const float4*)(epr + q * 68 + d4);
    float* op = Og + (((size_t)b * NL + q0w + q) * NH + h) * ND + d4;
    *(float4*)op = val;
  }
}

extern "C" void kernel_launch(void* const* d_in, const int* in_sizes, int n_in,
                              void* d_out, int out_size, void* d_ws, size_t ws_size,
                              hipStream_t stream) {
  const float* Q = (const float*)d_in[0];
  const float* K = (const float*)d_in[1];
  const float* V = (const float*)d_in[2];
  float* O = (float*)d_out;
  const size_t need = (size_t)32 * NCHUNK * RECSZ * sizeof(float);   // 42.6 MB
  if (ws_size >= need) {
    sattn_part<<<dim3(32 * NCHUNK), dim3(256), 0, stream>>>(Q, K, V, (float*)d_ws);
    sattn_combine<<<dim3(1024), dim3(256), 0, stream>>>((const float*)d_ws, O);
  } else {
    sattn_mono<<<dim3(32, 16), dim3(256), 0, stream>>>(Q, K, V, O);
  }
}